// Round 4
// baseline (491.411 us; speedup 1.0000x reference)
//
#include <hip/hip_runtime.h>

// B=8, N=16384 (H=W=128), D=128, WS=4 -> nW=1024, P=16 tokens/window, NH=2, dh=64.
// All GEMMs via v_mfma_f32_16x16x32_bf16. Weights pre-converted to bf16 in d_ws.
// Activations live in d_out and are updated in place stage by stage.

typedef unsigned short u16;
typedef unsigned int   u32;
typedef __attribute__((ext_vector_type(8))) short bf16x8;
typedef __attribute__((ext_vector_type(4))) float f32x4;

#define MFMA(a,b,c) __builtin_amdgcn_mfma_f32_16x16x32_bf16(a,b,c,0,0,0)

__device__ __forceinline__ u16 f2bf(float x) {           // RNE fp32->bf16
    u32 u = __float_as_uint(x);
    return (u16)((u + 0x7FFFu + ((u >> 16) & 1u)) >> 16);
}
__device__ __forceinline__ u32 pack2(float lo, float hi) {
    return (u32)f2bf(lo) | ((u32)f2bf(hi) << 16);
}
// tanh-form GELU via hw exp2 + rcp. |err| vs exact erf-GELU < ~1e-3.
__device__ __forceinline__ float gelu_fast(float x) {
    float t = x * fmaf(x * x, 0.044715f, 1.0f);
    float e = __builtin_amdgcn_exp2f(-2.3022078f * t);   // exp(-1.5957691*t)
    return x * __builtin_amdgcn_rcpf(1.0f + e);
}
__device__ __forceinline__ bf16x8 ldsfrag(const u16* base, int byte) {
    return *(const bf16x8*)((const char*)base + byte);
}
__device__ __forceinline__ bf16x8 ldg8(const u16* __restrict__ p) {
    return *(const bf16x8*)p;
}
// branch 1: image-order flat index; branch 2: roll(-2,-2)-mapped window-order index.
template <int BRANCH>
__device__ __forceinline__ int src_index(int wg, int tok) {
    int win = (wg << 3) + (tok >> 4), p = tok & 15;
    int r = ((win >> 5) << 2) | (p >> 2);
    int c = ((win & 31) << 2) | (p & 3);
    if (BRANCH == 1) return (r << 7) | c;
    int r2 = (r + 2) & 127, c2 = (c + 2) & 127;
    return ((((r2 >> 2) << 5) | (c2 >> 2)) << 4) | ((r2 & 3) << 2) | (c2 & 3);
}

// ---------------------------------------------------------------------------
// Weight fp32 -> bf16 prep. 393216 elements total, 8 segments, 8 elems/thread.
// ---------------------------------------------------------------------------
__global__ __launch_bounds__(256)
void cvt_weights(const float* __restrict__ qkv1, const float* __restrict__ o1,
                 const float* __restrict__ w11,  const float* __restrict__ w12,
                 const float* __restrict__ qkv2, const float* __restrict__ o2,
                 const float* __restrict__ w21,  const float* __restrict__ w22,
                 u16* __restrict__ dst)
{
    int e = (blockIdx.x * 256 + threadIdx.x) * 8;
    const float* src; int off;
    if      (e < 49152)  { src = qkv1; off = 0; }
    else if (e < 65536)  { src = o1;   off = 49152; }
    else if (e < 131072) { src = w11;  off = 65536; }
    else if (e < 196608) { src = w12;  off = 131072; }
    else if (e < 245760) { src = qkv2; off = 196608; }
    else if (e < 262144) { src = o2;   off = 245760; }
    else if (e < 327680) { src = w21;  off = 262144; }
    else                 { src = w22;  off = 327680; }
    float4 a = *(const float4*)(src + (e - off));
    float4 b = *(const float4*)(src + (e - off) + 4);
    uint4 o;
    o.x = pack2(a.x, a.y); o.y = pack2(a.z, a.w);
    o.z = pack2(b.x, b.y); o.w = pack2(b.z, b.w);
    *(uint4*)(dst + e) = o;
}

// ---------------------------------------------------------------------------
// Fused windowed MHSA. 1 block = 8 windows = 128 tokens. 512 threads (8 waves).
// ---------------------------------------------------------------------------
template <int BRANCH>
__global__ __launch_bounds__(512, 2)
void attn_mfma(const float* __restrict__ xin, const float* __restrict__ resin,
               float* __restrict__ resout,
               const float* __restrict__ ln_g, const float* __restrict__ ln_b,
               const u16* __restrict__ qkvw, const float* __restrict__ qkvb,
               const u16* __restrict__ ow,   const float* __restrict__ ob)
{
    __shared__ __align__(16) u16 xs [128 * 128];   // LN'd x, later attn-out (256 B stride)
    __shared__ __align__(16) u16 qls[128 * 128];   // q, later P
    __shared__ __align__(16) u16 kls[128 * 128];   // k
    __shared__ __align__(16) u16 vt [128 * 192];   // [dh][token], 384 B stride

    const int t  = threadIdx.x;
    const int wv = t >> 6, ln = t & 63, l15 = ln & 15, q4 = ln >> 4;
    const int bb = blockIdx.x >> 7, wg = blockIdx.x & 127;
    const int xa = (l15 & 7) << 4;

    // ---------- phase 0: gather + LayerNorm -> xs (bf16); zero vt pad ----------
    {
        int token = t >> 2, part = t & 3;
        int nsrc = src_index<BRANCH>(wg, token);
        const float* src = xin + ((size_t)bb * 16384 + nsrc) * 128 + part * 32;
        float v[32];
#pragma unroll
        for (int i = 0; i < 8; ++i) *(float4*)&v[i * 4] = ((const float4*)src)[i];
        float s = 0.f, s2 = 0.f;
#pragma unroll
        for (int i = 0; i < 32; ++i) { s += v[i]; s2 += v[i] * v[i]; }
        s  += __shfl_xor(s, 1, 4);  s  += __shfl_xor(s, 2, 4);
        s2 += __shfl_xor(s2, 1, 4); s2 += __shfl_xor(s2, 2, 4);
        float mu = s * (1.f / 128.f);
        float rstd = rsqrtf(s2 * (1.f / 128.f) - mu * mu + 1e-5f);
        int tx = (token & 7) << 4;
#pragma unroll
        for (int g = 0; g < 4; ++g) {
            uint4 u; u32* up = (u32*)&u;
#pragma unroll
            for (int j = 0; j < 4; ++j) {
                int d0 = part * 32 + g * 8 + j * 2;
                float a = (v[g * 8 + j * 2]     - mu) * rstd * ln_g[d0]     + ln_b[d0];
                float c = (v[g * 8 + j * 2 + 1] - mu) * rstd * ln_g[d0 + 1] + ln_b[d0 + 1];
                up[j] = (u32)f2bf(a) | ((u32)f2bf(c) << 16);
            }
            int byte = token * 256 + ((part * 64 + g * 16) ^ tx);
            *(uint4*)((char*)xs + byte) = u;
        }
        int row = t >> 2, g2 = t & 3;
        uint4 z = {0, 0, 0, 0};
#pragma unroll
        for (int i = 0; i < 2; ++i) {
            int byte = row * 384 + ((256 + g2 * 32 + i * 16) ^ ((row & 7) << 4));
            *(uint4*)((char*)vt + byte) = z;
        }
    }
    __syncthreads();

    // ---------- phase 1: QKV GEMM (M=128,N=384,K=128) ----------
#pragma unroll
    for (int i = 0; i < 3; ++i) {
        int n0 = (wv * 3 + i) * 16;
        int part = n0 >> 7, c0 = n0 & 127;
        float bias = qkvb[n0 + l15];
        f32x4 acc[8];
#pragma unroll
        for (int mf = 0; mf < 8; ++mf) acc[mf] = (f32x4){bias, bias, bias, bias};
#pragma unroll
        for (int kf = 0; kf < 4; ++kf) {
            bf16x8 bfr = ldg8(qkvw + (size_t)(n0 + l15) * 128 + kf * 32 + q4 * 8);
#pragma unroll
            for (int mf = 0; mf < 8; ++mf) {
                bf16x8 afr = ldsfrag(xs, (mf * 16 + l15) * 256 + ((kf * 64 + q4 * 16) ^ xa));
                acc[mf] = MFMA(afr, bfr, acc[mf]);
            }
        }
        if (part < 2) {                       // q (scaled) / k, token-major
            u16* dst = part ? kls : qls;
            float sc = part ? 1.f : 0.125f;
#pragma unroll
            for (int mf = 0; mf < 8; ++mf)
#pragma unroll
                for (int r = 0; r < 4; ++r) {
                    int tok = mf * 16 + q4 * 4 + r;
                    int byte = tok * 256 + ((2 * (c0 + l15)) ^ ((tok & 7) << 4));
                    dst[byte >> 1] = f2bf(acc[mf][r] * sc);
                }
        } else {                              // v -> vt[dh][token]
            int dh = c0 + l15, xr = (dh & 7) << 4;
#pragma unroll
            for (int mf = 0; mf < 8; ++mf) {
                int tok0 = mf * 16 + q4 * 4;
                u32 lo = pack2(acc[mf][0], acc[mf][1]);
                u32 hi = pack2(acc[mf][2], acc[mf][3]);
                int byte = dh * 384 + ((2 * tok0) ^ xr);
                *(uint2*)((char*)vt + byte) = make_uint2(lo, hi);
            }
        }
    }
    __syncthreads();

    // ---------- phase 2: scores S = mfma(Q, K^T) over dh=64 ----------
    f32x4 S[2];
#pragma unroll
    for (int s = 0; s < 2; ++s) {
        int pair = wv * 2 + s, win = pair >> 1, h = pair & 1;
        f32x4 z = {0.f, 0.f, 0.f, 0.f};
        int tok = win * 16 + l15;
#pragma unroll
        for (int kf = 0; kf < 2; ++kf) {
            int byte = tok * 256 + ((h * 128 + kf * 64 + q4 * 16) ^ xa);
            bf16x8 aq = ldsfrag(qls, byte);
            bf16x8 bk = ldsfrag(kls, byte);
            z = MFMA(aq, bk, z);
        }
        S[s] = z;
    }
    __syncthreads();

    // ---------- softmax in-register, P (bf16, K padded to 32) overlays qls ----------
#pragma unroll
    for (int s = 0; s < 2; ++s) {
        int pair = wv * 2 + s, win = pair >> 1, h = pair & 1;
#pragma unroll
        for (int r = 0; r < 4; ++r) {
            float v = S[s][r];
            float m = v;
            m = fmaxf(m, __shfl_xor(m, 1, 16)); m = fmaxf(m, __shfl_xor(m, 2, 16));
            m = fmaxf(m, __shfl_xor(m, 4, 16)); m = fmaxf(m, __shfl_xor(m, 8, 16));
            float e = __builtin_amdgcn_exp2f((v - m) * 1.44269504f);
            float sm = e;
            sm += __shfl_xor(sm, 1, 16); sm += __shfl_xor(sm, 2, 16);
            sm += __shfl_xor(sm, 4, 16); sm += __shfl_xor(sm, 8, 16);
            float p = e * __builtin_amdgcn_rcpf(sm);
            int tok = win * 16 + q4 * 4 + r, tx = (tok & 7) << 4;
            qls[(tok * 128 + ((h * 64 + l15 * 2)      ^ tx)) >> 1] = f2bf(p);
            qls[(tok * 128 + ((h * 64 + 32 + l15 * 2) ^ tx)) >> 1] = 0;
        }
    }
    __syncthreads();

    // ---------- phase 3: PV -> xs ----------
#pragma unroll
    for (int s = 0; s < 2; ++s) {
        int pair = wv * 2 + s, win = pair >> 1, h = pair & 1;
        bf16x8 ap = ldsfrag(qls, (win * 16 + l15) * 128 + ((h * 64 + q4 * 16) ^ xa));
#pragma unroll
        for (int nf = 0; nf < 4; ++nf) {
            int dh = h * 64 + nf * 16 + l15;
            bf16x8 bv = ldsfrag(vt, dh * 384 + ((win * 32 + q4 * 16) ^ xa));
            f32x4 z = {0.f, 0.f, 0.f, 0.f};
            f32x4 o = MFMA(ap, bv, z);
#pragma unroll
            for (int r = 0; r < 4; ++r) {
                int tok = win * 16 + q4 * 4 + r;
                xs[(tok * 256 + ((2 * dh) ^ ((tok & 7) << 4))) >> 1] = f2bf(o[r]);
            }
        }
    }
    __syncthreads();

    // ---------- phase 4: output projection + residual epilogue ----------
    {
        int n0 = wv * 16;
        float bias = ob[n0 + l15];
        f32x4 acc[8];
#pragma unroll
        for (int mf = 0; mf < 8; ++mf) acc[mf] = (f32x4){bias, bias, bias, bias};
#pragma unroll
        for (int kf = 0; kf < 4; ++kf) {
            bf16x8 bfr = ldg8(ow + (size_t)(n0 + l15) * 128 + kf * 32 + q4 * 8);
#pragma unroll
            for (int mf = 0; mf < 8; ++mf) {
                bf16x8 afr = ldsfrag(xs, (mf * 16 + l15) * 256 + ((kf * 64 + q4 * 16) ^ xa));
                acc[mf] = MFMA(afr, bfr, acc[mf]);
            }
        }
#pragma unroll
        for (int mf = 0; mf < 8; ++mf)
#pragma unroll
            for (int r = 0; r < 4; ++r) {
                int tok = mf * 16 + q4 * 4 + r;
                int nd = (BRANCH == 1) ? (wg * 128 + tok) : src_index<2>(wg, tok);
                size_t ridx = ((size_t)bb * 16384 + nd) * 128 + n0 + l15;
                float rv = resin[ridx];
                if (BRANCH == 1) rv = truncf(rv);
                resout[ridx] = rv + acc[mf][r];
            }
    }
}

// ---------------------------------------------------------------------------
// Fused MLP, in place. 1 block = 64 tokens, 4 waves. h1 chunked 4x128 cols,
// DOUBLE-BUFFERED: GEMM1(c+1) overlaps GEMM2(c); one barrier per chunk.
// LDS 48 KiB -> 3 blocks/CU; launch_bounds(256,3) -> ~170-reg cap, no spill.
// ---------------------------------------------------------------------------
#define GEMM1_CHUNK(cc, dst)                                                          \
    do {                                                                              \
        f32x4 acc1[4][2];                                                             \
        _Pragma("unroll") for (int nf = 0; nf < 2; ++nf) {                            \
            float bias = b1[(cc) * 128 + nb + nf * 16 + l15];                         \
            _Pragma("unroll") for (int mf = 0; mf < 4; ++mf)                          \
                acc1[mf][nf] = (f32x4){bias, bias, bias, bias};                       \
        }                                                                             \
        _Pragma("unroll") for (int kf = 0; kf < 4; ++kf) {                            \
            bf16x8 a_[4];                                                             \
            _Pragma("unroll") for (int mf = 0; mf < 4; ++mf)                          \
                a_[mf] = ldsfrag(xs, (mf * 16 + l15) * 256 + ((kf * 64 + q4 * 16) ^ xa)); \
            _Pragma("unroll") for (int nf = 0; nf < 2; ++nf) {                        \
                bf16x8 bfr = ldg8(w1 + (size_t)((cc) * 128 + nb + nf * 16 + l15) * 128 \
                                      + kf * 32 + q4 * 8);                            \
                _Pragma("unroll") for (int mf = 0; mf < 4; ++mf)                      \
                    acc1[mf][nf] = MFMA(a_[mf], bfr, acc1[mf][nf]);                   \
            }                                                                         \
        }                                                                             \
        _Pragma("unroll") for (int nf = 0; nf < 2; ++nf) {                            \
            int lc = nb + nf * 16 + l15;                                              \
            _Pragma("unroll") for (int mf = 0; mf < 4; ++mf)                          \
                _Pragma("unroll") for (int r = 0; r < 4; ++r) {                       \
                    int tok = mf * 16 + q4 * 4 + r;                                   \
                    (dst)[(tok * 256 + ((2 * lc) ^ ((tok & 7) << 4))) >> 1] =         \
                        f2bf(gelu_fast(acc1[mf][nf][r]));                             \
                }                                                                     \
        }                                                                             \
    } while (0)

#define GEMM2_CHUNK(cc, srcb)                                                         \
    do {                                                                              \
        _Pragma("unroll") for (int kf = 0; kf < 4; ++kf) {                            \
            bf16x8 a_[4];                                                             \
            _Pragma("unroll") for (int mf = 0; mf < 4; ++mf)                          \
                a_[mf] = ldsfrag((srcb), (mf * 16 + l15) * 256 + ((kf * 64 + q4 * 16) ^ xa)); \
            _Pragma("unroll") for (int nf = 0; nf < 2; ++nf) {                        \
                bf16x8 bfr = ldg8(w2 + (size_t)(nb + nf * 16 + l15) * 512             \
                                      + (cc) * 128 + kf * 32 + q4 * 8);               \
                _Pragma("unroll") for (int mf = 0; mf < 4; ++mf)                      \
                    acc2[mf][nf] = MFMA(a_[mf], bfr, acc2[mf][nf]);                   \
            }                                                                         \
        }                                                                             \
    } while (0)

__global__ __launch_bounds__(256, 3)
void mlp_mfma(float* __restrict__ buf,
              const float* __restrict__ ln_g, const float* __restrict__ ln_b,
              const u16* __restrict__ w1, const float* __restrict__ b1,
              const u16* __restrict__ w2, const float* __restrict__ b2)
{
    __shared__ __align__(16) u16 xs [64 * 128];   // 16 KiB
    __shared__ __align__(16) u16 h1a[64 * 128];   // 16 KiB
    __shared__ __align__(16) u16 h1b[64 * 128];   // 16 KiB

    const int t = threadIdx.x;
    const int wv = t >> 6, ln = t & 63, l15 = ln & 15, q4 = ln >> 4;
    const int xa = (l15 & 7) << 4;
    const size_t base = (size_t)blockIdx.x * 64 * 128;
    const int nb = wv * 32;     // this wave's 32 cols (GEMM1-chunk-local & GEMM2-out)

    // ---------- LN -> xs (bf16) ----------
    {
        int token = t >> 2, part = t & 3;
        const float* src = buf + base + token * 128 + part * 32;
        float v[32];
#pragma unroll
        for (int i = 0; i < 8; ++i) *(float4*)&v[i * 4] = ((const float4*)src)[i];
        float s = 0.f, s2 = 0.f;
#pragma unroll
        for (int i = 0; i < 32; ++i) { s += v[i]; s2 += v[i] * v[i]; }
        s  += __shfl_xor(s, 1, 4);  s  += __shfl_xor(s, 2, 4);
        s2 += __shfl_xor(s2, 1, 4); s2 += __shfl_xor(s2, 2, 4);
        float mu = s * (1.f / 128.f);
        float rstd = rsqrtf(s2 * (1.f / 128.f) - mu * mu + 1e-5f);
        int tx = (token & 7) << 4;
#pragma unroll
        for (int g = 0; g < 4; ++g) {
            uint4 u; u32* up = (u32*)&u;
#pragma unroll
            for (int j = 0; j < 4; ++j) {
                int d0 = part * 32 + g * 8 + j * 2;
                float a = (v[g * 8 + j * 2]     - mu) * rstd * ln_g[d0]     + ln_b[d0];
                float c = (v[g * 8 + j * 2 + 1] - mu) * rstd * ln_g[d0 + 1] + ln_b[d0 + 1];
                up[j] = (u32)f2bf(a) | ((u32)f2bf(c) << 16);
            }
            int byte = token * 256 + ((part * 64 + g * 16) ^ tx);
            *(uint4*)((char*)xs + byte) = u;
        }
    }
    __syncthreads();

    f32x4 acc2[4][2];
#pragma unroll
    for (int nf = 0; nf < 2; ++nf) {
        float bias = b2[nb + nf * 16 + l15];
#pragma unroll
        for (int mf = 0; mf < 4; ++mf) acc2[mf][nf] = (f32x4){bias, bias, bias, bias};
    }

    // software-pipelined chunks: GEMM1(c+1) issues loads before GEMM2(c) computes
    GEMM1_CHUNK(0, h1a);
    __syncthreads();
    GEMM1_CHUNK(1, h1b);
    GEMM2_CHUNK(0, h1a);
    __syncthreads();
    GEMM1_CHUNK(2, h1a);
    GEMM2_CHUNK(1, h1b);
    __syncthreads();
    GEMM1_CHUNK(3, h1b);
    GEMM2_CHUNK(2, h1a);
    __syncthreads();
    GEMM2_CHUNK(3, h1b);

    // ---------- epilogue: GELU + residual, in place ----------
#pragma unroll
    for (int nf = 0; nf < 2; ++nf) {
        int col = nb + nf * 16 + l15;
#pragma unroll
        for (int mf = 0; mf < 4; ++mf)
#pragma unroll
            for (int r = 0; r < 4; ++r) {
                int tok = mf * 16 + q4 * 4 + r;
                size_t idx = base + (size_t)tok * 128 + col;
                buf[idx] = gelu_fast(acc2[mf][nf][r]) + buf[idx];
            }
    }
}

extern "C" void kernel_launch(void* const* d_in, const int* in_sizes, int n_in,
                              void* d_out, int out_size, void* d_ws, size_t ws_size,
                              hipStream_t stream) {
    (void)in_sizes; (void)n_in; (void)out_size; (void)ws_size;
    const float* x      = (const float*)d_in[0];
    const float* ln1_g  = (const float*)d_in[1];
    const float* ln1_b  = (const float*)d_in[2];
    const float* ln2_g  = (const float*)d_in[3];
    const float* ln2_b  = (const float*)d_in[4];
    const float* ln3_g  = (const float*)d_in[5];
    const float* ln3_b  = (const float*)d_in[6];
    const float* ln4_g  = (const float*)d_in[7];
    const float* ln4_b  = (const float*)d_in[8];
    const float* qkv1_w = (const float*)d_in[9];
    const float* qkv1_b = (const float*)d_in[10];
    const float* out1_w = (const float*)d_in[11];
    const float* out1_b = (const float*)d_in[12];
    const float* qkv2_w = (const float*)d_in[13];
    const float* qkv2_b = (const float*)d_in[14];
    const float* out2_w = (const float*)d_in[15];
    const float* out2_b = (const float*)d_in[16];
    const float* mlp1_w1 = (const float*)d_in[17];
    const float* mlp1_b1 = (const float*)d_in[18];
    const float* mlp1_w2 = (const float*)d_in[19];
    const float* mlp1_b2 = (const float*)d_in[20];
    const float* mlp2_w1 = (const float*)d_in[21];
    const float* mlp2_b1 = (const float*)d_in[22];
    const float* mlp2_w2 = (const float*)d_in[23];
    const float* mlp2_b2 = (const float*)d_in[24];

    // bf16 weights in d_ws (786 KiB total)
    u16* wb = (u16*)d_ws;
    u16* qkv1bf = wb + 0;
    u16* out1bf = wb + 49152;
    u16* m1w1bf = wb + 65536;
    u16* m1w2bf = wb + 131072;
    u16* qkv2bf = wb + 196608;
    u16* out2bf = wb + 245760;
    u16* m2w1bf = wb + 262144;
    u16* m2w2bf = wb + 327680;

    float* out = (float*)d_out;   // activations: res1 -> out1 -> res2 -> out2, in place

    cvt_weights<<<dim3(192), dim3(256), 0, stream>>>(
        qkv1_w, out1_w, mlp1_w1, mlp1_w2, qkv2_w, out2_w, mlp2_w1, mlp2_w2, wb);

    // 1) W-MSA: res1 = trunc(x) + a1     (writes every element of d_out)
    attn_mfma<1><<<dim3(1024), dim3(512), 0, stream>>>(x, x, out,
        ln1_g, ln1_b, qkv1bf, qkv1_b, out1bf, out1_b);
    // 2) MLP1 (in place)
    mlp_mfma<<<dim3(2048), dim3(256), 0, stream>>>(out, ln2_g, ln2_b,
        m1w1bf, mlp1_b1, m1w2bf, mlp1_b2);
    // 3) SW-MSA: res2 = out1 + a2 (gather index == scatter index; block-local rows)
    attn_mfma<2><<<dim3(1024), dim3(512), 0, stream>>>(out, out, out,
        ln3_g, ln3_b, qkv2bf, qkv2_b, out2bf, out2_b);
    // 4) MLP2 (in place)
    mlp_mfma<<<dim3(2048), dim3(256), 0, stream>>>(out, ln4_g, ln4_b,
        m2w1bf, mlp2_b1, m2w2bf, mlp2_b2);
}

// Round 5
// 352.963 us; speedup vs baseline: 1.3922x; 1.3922x over previous
//
#include <hip/hip_runtime.h>

// B=8, N=16384 (H=W=128), D=128, WS=4 -> nW=1024, P=16 tokens/window, NH=2, dh=64.
// All GEMMs via v_mfma_f32_16x16x32_bf16. Weights pre-converted to bf16 in d_ws.
// Activations live in d_out and are updated in place stage by stage.

typedef unsigned short u16;
typedef unsigned int   u32;
typedef __attribute__((ext_vector_type(8))) short bf16x8;
typedef __attribute__((ext_vector_type(4))) float f32x4;

#define MFMA(a,b,c) __builtin_amdgcn_mfma_f32_16x16x32_bf16(a,b,c,0,0,0)

__device__ __forceinline__ u16 f2bf(float x) {           // RNE fp32->bf16
    u32 u = __float_as_uint(x);
    return (u16)((u + 0x7FFFu + ((u >> 16) & 1u)) >> 16);
}
__device__ __forceinline__ u32 pack2(float lo, float hi) {
    return (u32)f2bf(lo) | ((u32)f2bf(hi) << 16);
}
// tanh-form GELU via hw exp2 + rcp. |err| vs exact erf-GELU < ~1e-3.
__device__ __forceinline__ float gelu_fast(float x) {
    float t = x * fmaf(x * x, 0.044715f, 1.0f);
    float e = __builtin_amdgcn_exp2f(-2.3022078f * t);   // exp(-1.5957691*t)
    return x * __builtin_amdgcn_rcpf(1.0f + e);
}
__device__ __forceinline__ bf16x8 ldsfrag(const u16* base, int byte) {
    return *(const bf16x8*)((const char*)base + byte);
}
__device__ __forceinline__ bf16x8 ldg8(const u16* __restrict__ p) {
    return *(const bf16x8*)p;
}
// branch 1: image-order flat index; branch 2: roll(-2,-2)-mapped window-order index.
template <int BRANCH>
__device__ __forceinline__ int src_index(int wg, int tok) {
    int win = (wg << 3) + (tok >> 4), p = tok & 15;
    int r = ((win >> 5) << 2) | (p >> 2);
    int c = ((win & 31) << 2) | (p & 3);
    if (BRANCH == 1) return (r << 7) | c;
    int r2 = (r + 2) & 127, c2 = (c + 2) & 127;
    return ((((r2 >> 2) << 5) | (c2 >> 2)) << 4) | ((r2 & 3) << 2) | (c2 & 3);
}

// ---------------------------------------------------------------------------
// Weight fp32 -> bf16 prep. 393216 elements total, 8 segments, 8 elems/thread.
// ---------------------------------------------------------------------------
__global__ __launch_bounds__(256)
void cvt_weights(const float* __restrict__ qkv1, const float* __restrict__ o1,
                 const float* __restrict__ w11,  const float* __restrict__ w12,
                 const float* __restrict__ qkv2, const float* __restrict__ o2,
                 const float* __restrict__ w21,  const float* __restrict__ w22,
                 u16* __restrict__ dst)
{
    int e = (blockIdx.x * 256 + threadIdx.x) * 8;
    const float* src; int off;
    if      (e < 49152)  { src = qkv1; off = 0; }
    else if (e < 65536)  { src = o1;   off = 49152; }
    else if (e < 131072) { src = w11;  off = 65536; }
    else if (e < 196608) { src = w12;  off = 131072; }
    else if (e < 245760) { src = qkv2; off = 196608; }
    else if (e < 262144) { src = o2;   off = 245760; }
    else if (e < 327680) { src = w21;  off = 262144; }
    else                 { src = w22;  off = 327680; }
    float4 a = *(const float4*)(src + (e - off));
    float4 b = *(const float4*)(src + (e - off) + 4);
    uint4 o;
    o.x = pack2(a.x, a.y); o.y = pack2(a.z, a.w);
    o.z = pack2(b.x, b.y); o.w = pack2(b.z, b.w);
    *(uint4*)(dst + e) = o;
}

// ---------------------------------------------------------------------------
// Fused windowed MHSA. 1 block = 8 windows = 128 tokens. 512 threads (8 waves).
// ---------------------------------------------------------------------------
template <int BRANCH>
__global__ __launch_bounds__(512, 2)
void attn_mfma(const float* __restrict__ xin, const float* __restrict__ resin,
               float* __restrict__ resout,
               const float* __restrict__ ln_g, const float* __restrict__ ln_b,
               const u16* __restrict__ qkvw, const float* __restrict__ qkvb,
               const u16* __restrict__ ow,   const float* __restrict__ ob)
{
    __shared__ __align__(16) u16 xs [128 * 128];   // LN'd x, later attn-out (256 B stride)
    __shared__ __align__(16) u16 qls[128 * 128];   // q, later P
    __shared__ __align__(16) u16 kls[128 * 128];   // k
    __shared__ __align__(16) u16 vt [128 * 192];   // [dh][token], 384 B stride

    const int t  = threadIdx.x;
    const int wv = t >> 6, ln = t & 63, l15 = ln & 15, q4 = ln >> 4;
    const int bb = blockIdx.x >> 7, wg = blockIdx.x & 127;
    const int xa = (l15 & 7) << 4;

    // ---------- phase 0: gather + LayerNorm -> xs (bf16); zero vt pad ----------
    {
        int token = t >> 2, part = t & 3;
        int nsrc = src_index<BRANCH>(wg, token);
        const float* src = xin + ((size_t)bb * 16384 + nsrc) * 128 + part * 32;
        float v[32];
#pragma unroll
        for (int i = 0; i < 8; ++i) *(float4*)&v[i * 4] = ((const float4*)src)[i];
        float s = 0.f, s2 = 0.f;
#pragma unroll
        for (int i = 0; i < 32; ++i) { s += v[i]; s2 += v[i] * v[i]; }
        s  += __shfl_xor(s, 1, 4);  s  += __shfl_xor(s, 2, 4);
        s2 += __shfl_xor(s2, 1, 4); s2 += __shfl_xor(s2, 2, 4);
        float mu = s * (1.f / 128.f);
        float rstd = rsqrtf(s2 * (1.f / 128.f) - mu * mu + 1e-5f);
        int tx = (token & 7) << 4;
#pragma unroll
        for (int g = 0; g < 4; ++g) {
            uint4 u; u32* up = (u32*)&u;
#pragma unroll
            for (int j = 0; j < 4; ++j) {
                int d0 = part * 32 + g * 8 + j * 2;
                float a = (v[g * 8 + j * 2]     - mu) * rstd * ln_g[d0]     + ln_b[d0];
                float c = (v[g * 8 + j * 2 + 1] - mu) * rstd * ln_g[d0 + 1] + ln_b[d0 + 1];
                up[j] = (u32)f2bf(a) | ((u32)f2bf(c) << 16);
            }
            int byte = token * 256 + ((part * 64 + g * 16) ^ tx);
            *(uint4*)((char*)xs + byte) = u;
        }
        int row = t >> 2, g2 = t & 3;
        uint4 z = {0, 0, 0, 0};
#pragma unroll
        for (int i = 0; i < 2; ++i) {
            int byte = row * 384 + ((256 + g2 * 32 + i * 16) ^ ((row & 7) << 4));
            *(uint4*)((char*)vt + byte) = z;
        }
    }
    __syncthreads();

    // ---------- phase 1: QKV GEMM (M=128,N=384,K=128) ----------
#pragma unroll
    for (int i = 0; i < 3; ++i) {
        int n0 = (wv * 3 + i) * 16;
        int part = n0 >> 7, c0 = n0 & 127;
        float bias = qkvb[n0 + l15];
        f32x4 acc[8];
#pragma unroll
        for (int mf = 0; mf < 8; ++mf) acc[mf] = (f32x4){bias, bias, bias, bias};
#pragma unroll
        for (int kf = 0; kf < 4; ++kf) {
            bf16x8 bfr = ldg8(qkvw + (size_t)(n0 + l15) * 128 + kf * 32 + q4 * 8);
#pragma unroll
            for (int mf = 0; mf < 8; ++mf) {
                bf16x8 afr = ldsfrag(xs, (mf * 16 + l15) * 256 + ((kf * 64 + q4 * 16) ^ xa));
                acc[mf] = MFMA(afr, bfr, acc[mf]);
            }
        }
        if (part < 2) {                       // q (scaled) / k, token-major
            u16* dst = part ? kls : qls;
            float sc = part ? 1.f : 0.125f;
#pragma unroll
            for (int mf = 0; mf < 8; ++mf)
#pragma unroll
                for (int r = 0; r < 4; ++r) {
                    int tok = mf * 16 + q4 * 4 + r;
                    int byte = tok * 256 + ((2 * (c0 + l15)) ^ ((tok & 7) << 4));
                    dst[byte >> 1] = f2bf(acc[mf][r] * sc);
                }
        } else {                              // v -> vt[dh][token]
            int dh = c0 + l15, xr = (dh & 7) << 4;
#pragma unroll
            for (int mf = 0; mf < 8; ++mf) {
                int tok0 = mf * 16 + q4 * 4;
                u32 lo = pack2(acc[mf][0], acc[mf][1]);
                u32 hi = pack2(acc[mf][2], acc[mf][3]);
                int byte = dh * 384 + ((2 * tok0) ^ xr);
                *(uint2*)((char*)vt + byte) = make_uint2(lo, hi);
            }
        }
    }
    __syncthreads();

    // ---------- phase 2: scores S = mfma(Q, K^T) over dh=64 ----------
    f32x4 S[2];
#pragma unroll
    for (int s = 0; s < 2; ++s) {
        int pair = wv * 2 + s, win = pair >> 1, h = pair & 1;
        f32x4 z = {0.f, 0.f, 0.f, 0.f};
        int tok = win * 16 + l15;
#pragma unroll
        for (int kf = 0; kf < 2; ++kf) {
            int byte = tok * 256 + ((h * 128 + kf * 64 + q4 * 16) ^ xa);
            bf16x8 aq = ldsfrag(qls, byte);
            bf16x8 bk = ldsfrag(kls, byte);
            z = MFMA(aq, bk, z);
        }
        S[s] = z;
    }
    __syncthreads();

    // ---------- softmax in-register, P (bf16, K padded to 32) overlays qls ----------
#pragma unroll
    for (int s = 0; s < 2; ++s) {
        int pair = wv * 2 + s, win = pair >> 1, h = pair & 1;
#pragma unroll
        for (int r = 0; r < 4; ++r) {
            float v = S[s][r];
            float m = v;
            m = fmaxf(m, __shfl_xor(m, 1, 16)); m = fmaxf(m, __shfl_xor(m, 2, 16));
            m = fmaxf(m, __shfl_xor(m, 4, 16)); m = fmaxf(m, __shfl_xor(m, 8, 16));
            float e = __builtin_amdgcn_exp2f((v - m) * 1.44269504f);
            float sm = e;
            sm += __shfl_xor(sm, 1, 16); sm += __shfl_xor(sm, 2, 16);
            sm += __shfl_xor(sm, 4, 16); sm += __shfl_xor(sm, 8, 16);
            float p = e * __builtin_amdgcn_rcpf(sm);
            int tok = win * 16 + q4 * 4 + r, tx = (tok & 7) << 4;
            qls[(tok * 128 + ((h * 64 + l15 * 2)      ^ tx)) >> 1] = f2bf(p);
            qls[(tok * 128 + ((h * 64 + 32 + l15 * 2) ^ tx)) >> 1] = 0;
        }
    }
    __syncthreads();

    // ---------- phase 3: PV -> xs ----------
#pragma unroll
    for (int s = 0; s < 2; ++s) {
        int pair = wv * 2 + s, win = pair >> 1, h = pair & 1;
        bf16x8 ap = ldsfrag(qls, (win * 16 + l15) * 128 + ((h * 64 + q4 * 16) ^ xa));
#pragma unroll
        for (int nf = 0; nf < 4; ++nf) {
            int dh = h * 64 + nf * 16 + l15;
            bf16x8 bv = ldsfrag(vt, dh * 384 + ((win * 32 + q4 * 16) ^ xa));
            f32x4 z = {0.f, 0.f, 0.f, 0.f};
            f32x4 o = MFMA(ap, bv, z);
#pragma unroll
            for (int r = 0; r < 4; ++r) {
                int tok = win * 16 + q4 * 4 + r;
                xs[(tok * 256 + ((2 * dh) ^ ((tok & 7) << 4))) >> 1] = f2bf(o[r]);
            }
        }
    }
    __syncthreads();

    // ---------- phase 4: output projection + residual epilogue ----------
    {
        int n0 = wv * 16;
        float bias = ob[n0 + l15];
        f32x4 acc[8];
#pragma unroll
        for (int mf = 0; mf < 8; ++mf) acc[mf] = (f32x4){bias, bias, bias, bias};
#pragma unroll
        for (int kf = 0; kf < 4; ++kf) {
            bf16x8 bfr = ldg8(ow + (size_t)(n0 + l15) * 128 + kf * 32 + q4 * 8);
#pragma unroll
            for (int mf = 0; mf < 8; ++mf) {
                bf16x8 afr = ldsfrag(xs, (mf * 16 + l15) * 256 + ((kf * 64 + q4 * 16) ^ xa));
                acc[mf] = MFMA(afr, bfr, acc[mf]);
            }
        }
#pragma unroll
        for (int mf = 0; mf < 8; ++mf)
#pragma unroll
            for (int r = 0; r < 4; ++r) {
                int tok = mf * 16 + q4 * 4 + r;
                int nd = (BRANCH == 1) ? (wg * 128 + tok) : src_index<2>(wg, tok);
                size_t ridx = ((size_t)bb * 16384 + nd) * 128 + n0 + l15;
                float rv = resin[ridx];
                if (BRANCH == 1) rv = truncf(rv);
                resout[ridx] = rv + acc[mf][r];
            }
    }
}

// ---------------------------------------------------------------------------
// Fused MLP, in place. 1 block = 64 tokens, 4 waves. h1 chunked 4x128 cols,
// double-buffered; GEMM1(c+1) overlaps GEMM2(c).
// launch_bounds(256,2): 256-reg combined cap -> room for acc1+acc2+hoisted
// weight frags, NO SPILL (R3/R4 spilled at caps 128/170; WRITE_SIZE evidence).
// ---------------------------------------------------------------------------
#define GEMM1_CHUNK(cc, dst)                                                          \
    do {                                                                              \
        f32x4 acc1[4][2];                                                             \
        _Pragma("unroll") for (int nf = 0; nf < 2; ++nf) {                            \
            float bias = b1[(cc) * 128 + nb + nf * 16 + l15];                         \
            _Pragma("unroll") for (int mf = 0; mf < 4; ++mf)                          \
                acc1[mf][nf] = (f32x4){bias, bias, bias, bias};                       \
        }                                                                             \
        _Pragma("unroll") for (int kf = 0; kf < 4; ++kf) {                            \
            bf16x8 a_[4];                                                             \
            _Pragma("unroll") for (int mf = 0; mf < 4; ++mf)                          \
                a_[mf] = ldsfrag(xs, (mf * 16 + l15) * 256 + ((kf * 64 + q4 * 16) ^ xa)); \
            _Pragma("unroll") for (int nf = 0; nf < 2; ++nf) {                        \
                bf16x8 bfr = ldg8(w1 + (size_t)((cc) * 128 + nb + nf * 16 + l15) * 128 \
                                      + kf * 32 + q4 * 8);                            \
                _Pragma("unroll") for (int mf = 0; mf < 4; ++mf)                      \
                    acc1[mf][nf] = MFMA(a_[mf], bfr, acc1[mf][nf]);                   \
            }                                                                         \
        }                                                                             \
        _Pragma("unroll") for (int nf = 0; nf < 2; ++nf) {                            \
            int lc = nb + nf * 16 + l15;                                              \
            _Pragma("unroll") for (int mf = 0; mf < 4; ++mf)                          \
                _Pragma("unroll") for (int r = 0; r < 4; ++r) {                       \
                    int tok = mf * 16 + q4 * 4 + r;                                   \
                    (dst)[(tok * 256 + ((2 * lc) ^ ((tok & 7) << 4))) >> 1] =         \
                        f2bf(gelu_fast(acc1[mf][nf][r]));                             \
                }                                                                     \
        }                                                                             \
    } while (0)

#define GEMM2_CHUNK(cc, srcb)                                                         \
    do {                                                                              \
        _Pragma("unroll") for (int kf = 0; kf < 4; ++kf) {                            \
            bf16x8 a_[4];                                                             \
            _Pragma("unroll") for (int mf = 0; mf < 4; ++mf)                          \
                a_[mf] = ldsfrag((srcb), (mf * 16 + l15) * 256 + ((kf * 64 + q4 * 16) ^ xa)); \
            _Pragma("unroll") for (int nf = 0; nf < 2; ++nf) {                        \
                bf16x8 bfr = ldg8(w2 + (size_t)(nb + nf * 16 + l15) * 512             \
                                      + (cc) * 128 + kf * 32 + q4 * 8);               \
                _Pragma("unroll") for (int mf = 0; mf < 4; ++mf)                      \
                    acc2[mf][nf] = MFMA(a_[mf], bfr, acc2[mf][nf]);                   \
            }                                                                         \
        }                                                                             \
    } while (0)

__global__ __launch_bounds__(256, 2)
void mlp_mfma(float* __restrict__ buf,
              const float* __restrict__ ln_g, const float* __restrict__ ln_b,
              const u16* __restrict__ w1, const float* __restrict__ b1,
              const u16* __restrict__ w2, const float* __restrict__ b2)
{
    __shared__ __align__(16) u16 xs [64 * 128];   // 16 KiB
    __shared__ __align__(16) u16 h1a[64 * 128];   // 16 KiB
    __shared__ __align__(16) u16 h1b[64 * 128];   // 16 KiB

    const int t = threadIdx.x;
    const int wv = t >> 6, ln = t & 63, l15 = ln & 15, q4 = ln >> 4;
    const int xa = (l15 & 7) << 4;
    const size_t base = (size_t)blockIdx.x * 64 * 128;
    const int nb = wv * 32;     // this wave's 32 cols (GEMM1-chunk-local & GEMM2-out)

    // ---------- LN -> xs (bf16) ----------
    {
        int token = t >> 2, part = t & 3;
        const float* src = buf + base + token * 128 + part * 32;
        float v[32];
#pragma unroll
        for (int i = 0; i < 8; ++i) *(float4*)&v[i * 4] = ((const float4*)src)[i];
        float s = 0.f, s2 = 0.f;
#pragma unroll
        for (int i = 0; i < 32; ++i) { s += v[i]; s2 += v[i] * v[i]; }
        s  += __shfl_xor(s, 1, 4);  s  += __shfl_xor(s, 2, 4);
        s2 += __shfl_xor(s2, 1, 4); s2 += __shfl_xor(s2, 2, 4);
        float mu = s * (1.f / 128.f);
        float rstd = rsqrtf(s2 * (1.f / 128.f) - mu * mu + 1e-5f);
        int tx = (token & 7) << 4;
#pragma unroll
        for (int g = 0; g < 4; ++g) {
            uint4 u; u32* up = (u32*)&u;
#pragma unroll
            for (int j = 0; j < 4; ++j) {
                int d0 = part * 32 + g * 8 + j * 2;
                float a = (v[g * 8 + j * 2]     - mu) * rstd * ln_g[d0]     + ln_b[d0];
                float c = (v[g * 8 + j * 2 + 1] - mu) * rstd * ln_g[d0 + 1] + ln_b[d0 + 1];
                up[j] = (u32)f2bf(a) | ((u32)f2bf(c) << 16);
            }
            int byte = token * 256 + ((part * 64 + g * 16) ^ tx);
            *(uint4*)((char*)xs + byte) = u;
        }
    }
    __syncthreads();

    f32x4 acc2[4][2];
#pragma unroll
    for (int nf = 0; nf < 2; ++nf) {
        float bias = b2[nb + nf * 16 + l15];
#pragma unroll
        for (int mf = 0; mf < 4; ++mf) acc2[mf][nf] = (f32x4){bias, bias, bias, bias};
    }

    // software-pipelined chunks: GEMM1(c+1) issues loads before GEMM2(c) computes
    GEMM1_CHUNK(0, h1a);
    __syncthreads();
    GEMM1_CHUNK(1, h1b);
    GEMM2_CHUNK(0, h1a);
    __syncthreads();
    GEMM1_CHUNK(2, h1a);
    GEMM2_CHUNK(1, h1b);
    __syncthreads();
    GEMM1_CHUNK(3, h1b);
    GEMM2_CHUNK(2, h1a);
    __syncthreads();
    GEMM2_CHUNK(3, h1b);

    // ---------- epilogue: GELU + residual, in place ----------
#pragma unroll
    for (int nf = 0; nf < 2; ++nf) {
        int col = nb + nf * 16 + l15;
#pragma unroll
        for (int mf = 0; mf < 4; ++mf)
#pragma unroll
            for (int r = 0; r < 4; ++r) {
                int tok = mf * 16 + q4 * 4 + r;
                size_t idx = base + (size_t)tok * 128 + col;
                buf[idx] = gelu_fast(acc2[mf][nf][r]) + buf[idx];
            }
    }
}

extern "C" void kernel_launch(void* const* d_in, const int* in_sizes, int n_in,
                              void* d_out, int out_size, void* d_ws, size_t ws_size,
                              hipStream_t stream) {
    (void)in_sizes; (void)n_in; (void)out_size; (void)ws_size;
    const float* x      = (const float*)d_in[0];
    const float* ln1_g  = (const float*)d_in[1];
    const float* ln1_b  = (const float*)d_in[2];
    const float* ln2_g  = (const float*)d_in[3];
    const float* ln2_b  = (const float*)d_in[4];
    const float* ln3_g  = (const float*)d_in[5];
    const float* ln3_b  = (const float*)d_in[6];
    const float* ln4_g  = (const float*)d_in[7];
    const float* ln4_b  = (const float*)d_in[8];
    const float* qkv1_w = (const float*)d_in[9];
    const float* qkv1_b = (const float*)d_in[10];
    const float* out1_w = (const float*)d_in[11];
    const float* out1_b = (const float*)d_in[12];
    const float* qkv2_w = (const float*)d_in[13];
    const float* qkv2_b = (const float*)d_in[14];
    const float* out2_w = (const float*)d_in[15];
    const float* out2_b = (const float*)d_in[16];
    const float* mlp1_w1 = (const float*)d_in[17];
    const float* mlp1_b1 = (const float*)d_in[18];
    const float* mlp1_w2 = (const float*)d_in[19];
    const float* mlp1_b2 = (const float*)d_in[20];
    const float* mlp2_w1 = (const float*)d_in[21];
    const float* mlp2_b1 = (const float*)d_in[22];
    const float* mlp2_w2 = (const float*)d_in[23];
    const float* mlp2_b2 = (const float*)d_in[24];

    // bf16 weights in d_ws (786 KiB total)
    u16* wb = (u16*)d_ws;
    u16* qkv1bf = wb + 0;
    u16* out1bf = wb + 49152;
    u16* m1w1bf = wb + 65536;
    u16* m1w2bf = wb + 131072;
    u16* qkv2bf = wb + 196608;
    u16* out2bf = wb + 245760;
    u16* m2w1bf = wb + 262144;
    u16* m2w2bf = wb + 327680;

    float* out = (float*)d_out;   // activations: res1 -> out1 -> res2 -> out2, in place

    cvt_weights<<<dim3(192), dim3(256), 0, stream>>>(
        qkv1_w, out1_w, mlp1_w1, mlp1_w2, qkv2_w, out2_w, mlp2_w1, mlp2_w2, wb);

    // 1) W-MSA: res1 = trunc(x) + a1     (writes every element of d_out)
    attn_mfma<1><<<dim3(1024), dim3(512), 0, stream>>>(x, x, out,
        ln1_g, ln1_b, qkv1bf, qkv1_b, out1bf, out1_b);
    // 2) MLP1 (in place)
    mlp_mfma<<<dim3(2048), dim3(256), 0, stream>>>(out, ln2_g, ln2_b,
        m1w1bf, mlp1_b1, m1w2bf, mlp1_b2);
    // 3) SW-MSA: res2 = out1 + a2 (gather index == scatter index; block-local rows)
    attn_mfma<2><<<dim3(1024), dim3(512), 0, stream>>>(out, out, out,
        ln3_g, ln3_b, qkv2bf, qkv2_b, out2bf, out2_b);
    // 4) MLP2 (in place)
    mlp_mfma<<<dim3(2048), dim3(256), 0, stream>>>(out, ln4_g, ln4_b,
        m2w1bf, mlp2_b1, m2w2bf, mlp2_b2);
}

// Round 6
// 351.218 us; speedup vs baseline: 1.3992x; 1.0050x over previous
//
#include <hip/hip_runtime.h>

// B=8, N=16384 (H=W=128), D=128, WS=4 -> nW=1024, P=16 tokens/window, NH=2, dh=64.
// Two fused kernels: K1 = LN1+W-MSA+res1(LDS)+LN2+MLP1 -> out1
//                    K2 = LN3+SW-MSA+res2(LDS)+LN4+MLP2 -> out2 (in place on d_out)
// All GEMMs via v_mfma_f32_16x16x32_bf16; weights pre-converted to bf16 in d_ws.

typedef unsigned short u16;
typedef unsigned int   u32;
typedef __attribute__((ext_vector_type(8))) short bf16x8;
typedef __attribute__((ext_vector_type(4))) float f32x4;

#define MFMA(a,b,c) __builtin_amdgcn_mfma_f32_16x16x32_bf16(a,b,c,0,0,0)

__device__ __forceinline__ u16 f2bf(float x) {           // RNE fp32->bf16
    u32 u = __float_as_uint(x);
    return (u16)((u + 0x7FFFu + ((u >> 16) & 1u)) >> 16);
}
__device__ __forceinline__ u32 pack2(float lo, float hi) {
    return (u32)f2bf(lo) | ((u32)f2bf(hi) << 16);
}
// tanh-form GELU via hw exp2 + rcp. |err| vs exact erf-GELU < ~1e-3.
__device__ __forceinline__ float gelu_fast(float x) {
    float t = x * fmaf(x * x, 0.044715f, 1.0f);
    float e = __builtin_amdgcn_exp2f(-2.3022078f * t);   // exp(-1.5957691*t)
    return x * __builtin_amdgcn_rcpf(1.0f + e);
}
__device__ __forceinline__ bf16x8 ldsfrag(const u16* base, int byte) {
    return *(const bf16x8*)((const char*)base + byte);
}
__device__ __forceinline__ bf16x8 ldg8(const u16* __restrict__ p) {
    return *(const bf16x8*)p;
}
// branch 1: image-order flat index; branch 2: roll(-2,-2)-mapped window-order index.
template <int BRANCH>
__device__ __forceinline__ int src_index(int wg, int tok) {
    int win = (wg << 3) + (tok >> 4), p = tok & 15;
    int r = ((win >> 5) << 2) | (p >> 2);
    int c = ((win & 31) << 2) | (p & 3);
    if (BRANCH == 1) return (r << 7) | c;
    int r2 = (r + 2) & 127, c2 = (c + 2) & 127;
    return ((((r2 >> 2) << 5) | (c2 >> 2)) << 4) | ((r2 & 3) << 2) | (c2 & 3);
}

// ---------------------------------------------------------------------------
// Weight fp32 -> bf16 prep. 393216 elements total, 8 segments, 8 elems/thread.
// ---------------------------------------------------------------------------
__global__ __launch_bounds__(256)
void cvt_weights(const float* __restrict__ qkv1, const float* __restrict__ o1,
                 const float* __restrict__ w11,  const float* __restrict__ w12,
                 const float* __restrict__ qkv2, const float* __restrict__ o2,
                 const float* __restrict__ w21,  const float* __restrict__ w22,
                 u16* __restrict__ dst)
{
    int e = (blockIdx.x * 256 + threadIdx.x) * 8;
    const float* src; int off;
    if      (e < 49152)  { src = qkv1; off = 0; }
    else if (e < 65536)  { src = o1;   off = 49152; }
    else if (e < 131072) { src = w11;  off = 65536; }
    else if (e < 196608) { src = w12;  off = 131072; }
    else if (e < 245760) { src = qkv2; off = 196608; }
    else if (e < 262144) { src = o2;   off = 245760; }
    else if (e < 327680) { src = w21;  off = 262144; }
    else                 { src = w22;  off = 327680; }
    float4 a = *(const float4*)(src + (e - off));
    float4 b = *(const float4*)(src + (e - off) + 4);
    uint4 o;
    o.x = pack2(a.x, a.y); o.y = pack2(a.z, a.w);
    o.z = pack2(b.x, b.y); o.w = pack2(b.z, b.w);
    *(uint4*)(dst + e) = o;
}

// ---------------------------------------------------------------------------
// Fused half-block: windowed MHSA + residual (LDS) + LN_B + MLP.
// 1 block = 8 windows = 128 tokens (contiguous window-order rows for BRANCH 1;
// the roll-mapped bijection set for BRANCH 2). 512 threads (8 waves).
// LDS 144 KiB: xs 32K | qls 32K | kls 32K | vt 48K, with overlays:
//   resf (fp32 res1/res2) = qls+kls region (64K), h1 chunk = vt region (32K).
// ---------------------------------------------------------------------------
template <int BRANCH>
__global__ __launch_bounds__(512, 2)
void swin_fused(const float* __restrict__ xin,   // LN_A source (x or out1)
                const float* __restrict__ resin, // residual source (x or out1)
                float* __restrict__ resout,      // output (out1 or out2)
                const float* __restrict__ lnA_g, const float* __restrict__ lnA_b,
                const float* __restrict__ lnB_g, const float* __restrict__ lnB_b,
                const u16* __restrict__ qkvw, const float* __restrict__ qkvb,
                const u16* __restrict__ ow,   const float* __restrict__ ob,
                const u16* __restrict__ w1,   const float* __restrict__ b1,
                const u16* __restrict__ w2,   const float* __restrict__ b2)
{
    __shared__ __align__(16) char smem[147456];
    u16*   xs   = (u16*)smem;             // [128 tok][128] bf16, 256B stride, XOR swz
    u16*   qls  = (u16*)(smem + 32768);   // q, later P
    u16*   kls  = (u16*)(smem + 65536);   // k
    u16*   vt   = (u16*)(smem + 98304);   // [dh][tok] bf16, 384B stride
    float* resf = (float*)(smem + 32768); // overlay qls+kls: [128 tok][128] fp32, 512B stride
    u16*   h1   = (u16*)(smem + 98304);   // overlay vt: one 128-col h1 chunk

    const int t  = threadIdx.x;
    const int wv = t >> 6, ln = t & 63, l15 = ln & 15, q4 = ln >> 4;
    const int bb = blockIdx.x >> 7, wg = blockIdx.x & 127;
    const int xa = (l15 & 7) << 4;
    const size_t gbase = (size_t)bb * 16384;

    // ---------- phase 0: gather + LN_A -> xs (bf16); zero vt pad ----------
    {
        int token = t >> 2, part = t & 3;
        int nsrc = src_index<BRANCH>(wg, token);
        const float* src = xin + (gbase + nsrc) * 128 + part * 32;
        float v[32];
#pragma unroll
        for (int i = 0; i < 8; ++i) *(float4*)&v[i * 4] = ((const float4*)src)[i];
        float s = 0.f, s2 = 0.f;
#pragma unroll
        for (int i = 0; i < 32; ++i) { s += v[i]; s2 += v[i] * v[i]; }
        s  += __shfl_xor(s, 1, 4);  s  += __shfl_xor(s, 2, 4);
        s2 += __shfl_xor(s2, 1, 4); s2 += __shfl_xor(s2, 2, 4);
        float mu = s * (1.f / 128.f);
        float rstd = rsqrtf(s2 * (1.f / 128.f) - mu * mu + 1e-5f);
        int tx = (token & 7) << 4;
#pragma unroll
        for (int g = 0; g < 4; ++g) {
            uint4 u; u32* up = (u32*)&u;
#pragma unroll
            for (int j = 0; j < 4; ++j) {
                int d0 = part * 32 + g * 8 + j * 2;
                float a = (v[g * 8 + j * 2]     - mu) * rstd * lnA_g[d0]     + lnA_b[d0];
                float c = (v[g * 8 + j * 2 + 1] - mu) * rstd * lnA_g[d0 + 1] + lnA_b[d0 + 1];
                up[j] = pack2(a, c);
            }
            int byte = token * 256 + ((part * 64 + g * 16) ^ tx);
            *(uint4*)((char*)xs + byte) = u;
        }
        int row = t >> 2, g2 = t & 3;
        uint4 z = {0, 0, 0, 0};
#pragma unroll
        for (int i = 0; i < 2; ++i) {
            int byte = row * 384 + ((256 + g2 * 32 + i * 16) ^ ((row & 7) << 4));
            *(uint4*)((char*)vt + byte) = z;
        }
    }
    __syncthreads();

    // ---------- phase 1: QKV GEMM (M=128,N=384,K=128) ----------
#pragma unroll
    for (int i = 0; i < 3; ++i) {
        int n0 = (wv * 3 + i) * 16;
        int part = n0 >> 7, c0 = n0 & 127;
        float bias = qkvb[n0 + l15];
        f32x4 acc[8];
#pragma unroll
        for (int mf = 0; mf < 8; ++mf) acc[mf] = (f32x4){bias, bias, bias, bias};
#pragma unroll
        for (int kf = 0; kf < 4; ++kf) {
            bf16x8 bfr = ldg8(qkvw + (size_t)(n0 + l15) * 128 + kf * 32 + q4 * 8);
#pragma unroll
            for (int mf = 0; mf < 8; ++mf) {
                bf16x8 afr = ldsfrag(xs, (mf * 16 + l15) * 256 + ((kf * 64 + q4 * 16) ^ xa));
                acc[mf] = MFMA(afr, bfr, acc[mf]);
            }
        }
        if (part < 2) {                       // q (scaled) / k, token-major
            u16* dst = part ? kls : qls;
            float sc = part ? 1.f : 0.125f;
#pragma unroll
            for (int mf = 0; mf < 8; ++mf)
#pragma unroll
                for (int r = 0; r < 4; ++r) {
                    int tok = mf * 16 + q4 * 4 + r;
                    int byte = tok * 256 + ((2 * (c0 + l15)) ^ ((tok & 7) << 4));
                    dst[byte >> 1] = f2bf(acc[mf][r] * sc);
                }
        } else {                              // v -> vt[dh][token]
            int dh = c0 + l15, xr = (dh & 7) << 4;
#pragma unroll
            for (int mf = 0; mf < 8; ++mf) {
                int tok0 = mf * 16 + q4 * 4;
                u32 lo = pack2(acc[mf][0], acc[mf][1]);
                u32 hi = pack2(acc[mf][2], acc[mf][3]);
                int byte = dh * 384 + ((2 * tok0) ^ xr);
                *(uint2*)((char*)vt + byte) = make_uint2(lo, hi);
            }
        }
    }
    __syncthreads();

    // ---------- phase 2: scores S = mfma(Q, K^T) over dh=64 ----------
    f32x4 S[2];
#pragma unroll
    for (int s = 0; s < 2; ++s) {
        int pair = wv * 2 + s, win = pair >> 1, h = pair & 1;
        f32x4 z = {0.f, 0.f, 0.f, 0.f};
        int tok = win * 16 + l15;
#pragma unroll
        for (int kf = 0; kf < 2; ++kf) {
            int byte = tok * 256 + ((h * 128 + kf * 64 + q4 * 16) ^ xa);
            bf16x8 aq = ldsfrag(qls, byte);
            bf16x8 bk = ldsfrag(kls, byte);
            z = MFMA(aq, bk, z);
        }
        S[s] = z;
    }
    __syncthreads();   // all q reads done before P overlays qls

    // ---------- softmax in-register, P (bf16, K padded to 32) overlays qls ----------
#pragma unroll
    for (int s = 0; s < 2; ++s) {
        int pair = wv * 2 + s, win = pair >> 1, h = pair & 1;
#pragma unroll
        for (int r = 0; r < 4; ++r) {
            float v = S[s][r];
            float m = v;
            m = fmaxf(m, __shfl_xor(m, 1, 16)); m = fmaxf(m, __shfl_xor(m, 2, 16));
            m = fmaxf(m, __shfl_xor(m, 4, 16)); m = fmaxf(m, __shfl_xor(m, 8, 16));
            float e = __builtin_amdgcn_exp2f((v - m) * 1.44269504f);
            float sm = e;
            sm += __shfl_xor(sm, 1, 16); sm += __shfl_xor(sm, 2, 16);
            sm += __shfl_xor(sm, 4, 16); sm += __shfl_xor(sm, 8, 16);
            float p = e * __builtin_amdgcn_rcpf(sm);
            int tok = win * 16 + q4 * 4 + r, tx = (tok & 7) << 4;
            qls[(tok * 128 + ((h * 64 + l15 * 2)      ^ tx)) >> 1] = f2bf(p);
            qls[(tok * 128 + ((h * 64 + 32 + l15 * 2) ^ tx)) >> 1] = 0;
        }
    }
    __syncthreads();

    // ---------- phase 3: PV -> xs (attn-out bf16) ----------
#pragma unroll
    for (int s = 0; s < 2; ++s) {
        int pair = wv * 2 + s, win = pair >> 1, h = pair & 1;
        bf16x8 ap = ldsfrag(qls, (win * 16 + l15) * 128 + ((h * 64 + q4 * 16) ^ xa));
#pragma unroll
        for (int nf = 0; nf < 4; ++nf) {
            int dh = h * 64 + nf * 16 + l15;
            bf16x8 bv = ldsfrag(vt, dh * 384 + ((win * 32 + q4 * 16) ^ xa));
            f32x4 z = {0.f, 0.f, 0.f, 0.f};
            f32x4 o = MFMA(ap, bv, z);
#pragma unroll
            for (int r = 0; r < 4; ++r) {
                int tok = win * 16 + q4 * 4 + r;
                xs[(tok * 256 + ((2 * dh) ^ ((tok & 7) << 4))) >> 1] = f2bf(o[r]);
            }
        }
    }
    __syncthreads();

    // ---------- phase 4: output projection + residual -> resf (LDS fp32) ----------
    {
        int n0 = wv * 16;
        float bias = ob[n0 + l15];
        f32x4 acc[8];
#pragma unroll
        for (int mf = 0; mf < 8; ++mf) acc[mf] = (f32x4){bias, bias, bias, bias};
#pragma unroll
        for (int kf = 0; kf < 4; ++kf) {
            bf16x8 bfr = ldg8(ow + (size_t)(n0 + l15) * 128 + kf * 32 + q4 * 8);
#pragma unroll
            for (int mf = 0; mf < 8; ++mf) {
                bf16x8 afr = ldsfrag(xs, (mf * 16 + l15) * 256 + ((kf * 64 + q4 * 16) ^ xa));
                acc[mf] = MFMA(afr, bfr, acc[mf]);
            }
        }
#pragma unroll
        for (int mf = 0; mf < 8; ++mf)
#pragma unroll
            for (int r = 0; r < 4; ++r) {
                int tok = mf * 16 + q4 * 4 + r;
                int nd = (BRANCH == 1) ? (wg * 128 + tok) : src_index<2>(wg, tok);
                float rv = resin[(gbase + nd) * 128 + n0 + l15];
                if (BRANCH == 1) rv = truncf(rv);
                int byte = tok * 512 + ((4 * (n0 + l15)) ^ ((tok & 7) << 4));
                *(float*)((char*)resf + byte) = rv + acc[mf][r];
            }
    }
    __syncthreads();

    // ---------- phase 5: LN_B over resf -> xs (bf16) ----------
    {
        int token = t >> 2, part = t & 3;
        int xtok = (token & 7) << 4;
        float v[32];
#pragma unroll
        for (int g = 0; g < 8; ++g)
            *(float4*)&v[g * 4] =
                *(const float4*)((char*)resf + token * 512 + ((part * 128 + g * 16) ^ xtok));
        float s = 0.f, s2 = 0.f;
#pragma unroll
        for (int i = 0; i < 32; ++i) { s += v[i]; s2 += v[i] * v[i]; }
        s  += __shfl_xor(s, 1, 4);  s  += __shfl_xor(s, 2, 4);
        s2 += __shfl_xor(s2, 1, 4); s2 += __shfl_xor(s2, 2, 4);
        float mu = s * (1.f / 128.f);
        float rstd = rsqrtf(s2 * (1.f / 128.f) - mu * mu + 1e-5f);
#pragma unroll
        for (int g = 0; g < 4; ++g) {
            uint4 u; u32* up = (u32*)&u;
#pragma unroll
            for (int j = 0; j < 4; ++j) {
                int d0 = part * 32 + g * 8 + j * 2;
                float a = (v[g * 8 + j * 2]     - mu) * rstd * lnB_g[d0]     + lnB_b[d0];
                float c = (v[g * 8 + j * 2 + 1] - mu) * rstd * lnB_g[d0 + 1] + lnB_b[d0 + 1];
                up[j] = pack2(a, c);
            }
            int byte = token * 256 + ((part * 64 + g * 16) ^ xtok);
            *(uint4*)((char*)xs + byte) = u;
        }
    }
    __syncthreads();

    // ---------- phase 6: MLP. 4 chunks x 128 h1-cols; wave owns 16 cols ----------
    const int nm = wv * 16;          // wave's col slice (GEMM1 chunk-local & GEMM2 out)
    f32x4 acc2[8];
    {
        float bias = b2[nm + l15];
#pragma unroll
        for (int mf = 0; mf < 8; ++mf) acc2[mf] = (f32x4){bias, bias, bias, bias};
    }
#pragma unroll 1
    for (int c = 0; c < 4; ++c) {
        // GEMM1 chunk c: acc1 = LN_B(res) @ W1[c*128+nm ..]^T + b1  (reads xs, w1)
        f32x4 acc1[8];
        {
            float bias = b1[c * 128 + nm + l15];
#pragma unroll
            for (int mf = 0; mf < 8; ++mf) acc1[mf] = (f32x4){bias, bias, bias, bias};
        }
#pragma unroll
        for (int kf = 0; kf < 4; ++kf) {
            bf16x8 bfr = ldg8(w1 + (size_t)(c * 128 + nm + l15) * 128 + kf * 32 + q4 * 8);
#pragma unroll
            for (int mf = 0; mf < 8; ++mf) {
                bf16x8 afr = ldsfrag(xs, (mf * 16 + l15) * 256 + ((kf * 64 + q4 * 16) ^ xa));
                acc1[mf] = MFMA(afr, bfr, acc1[mf]);
            }
        }
        __syncthreads();   // prior GEMM2 reads of h1 complete
#pragma unroll
        for (int mf = 0; mf < 8; ++mf)
#pragma unroll
            for (int r = 0; r < 4; ++r) {
                int tok = mf * 16 + q4 * 4 + r;
                h1[(tok * 256 + ((2 * (nm + l15)) ^ ((tok & 7) << 4))) >> 1] =
                    f2bf(gelu_fast(acc1[mf][r]));
            }
        __syncthreads();   // h1 chunk ready
        // GEMM2 partial: acc2 += h1 @ W2[nm.., c*128..]^T
#pragma unroll
        for (int kf = 0; kf < 4; ++kf) {
            bf16x8 bfr = ldg8(w2 + (size_t)(nm + l15) * 512 + c * 128 + kf * 32 + q4 * 8);
#pragma unroll
            for (int mf = 0; mf < 8; ++mf) {
                bf16x8 afr = ldsfrag(h1, (mf * 16 + l15) * 256 + ((kf * 64 + q4 * 16) ^ xa));
                acc2[mf] = MFMA(afr, bfr, acc2[mf]);
            }
        }
    }

    // ---------- phase 7: out = gelu(acc2) + resf -> global ----------
#pragma unroll
    for (int mf = 0; mf < 8; ++mf)
#pragma unroll
        for (int r = 0; r < 4; ++r) {
            int tok = mf * 16 + q4 * 4 + r;
            int nd = (BRANCH == 1) ? (wg * 128 + tok) : src_index<2>(wg, tok);
            float res = *(const float*)((char*)resf +
                            tok * 512 + ((4 * (nm + l15)) ^ ((tok & 7) << 4)));
            resout[(gbase + nd) * 128 + nm + l15] = gelu_fast(acc2[mf][r]) + res;
        }
}

extern "C" void kernel_launch(void* const* d_in, const int* in_sizes, int n_in,
                              void* d_out, int out_size, void* d_ws, size_t ws_size,
                              hipStream_t stream) {
    (void)in_sizes; (void)n_in; (void)out_size; (void)ws_size;
    const float* x      = (const float*)d_in[0];
    const float* ln1_g  = (const float*)d_in[1];
    const float* ln1_b  = (const float*)d_in[2];
    const float* ln2_g  = (const float*)d_in[3];
    const float* ln2_b  = (const float*)d_in[4];
    const float* ln3_g  = (const float*)d_in[5];
    const float* ln3_b  = (const float*)d_in[6];
    const float* ln4_g  = (const float*)d_in[7];
    const float* ln4_b  = (const float*)d_in[8];
    const float* qkv1_w = (const float*)d_in[9];
    const float* qkv1_b = (const float*)d_in[10];
    const float* out1_w = (const float*)d_in[11];
    const float* out1_b = (const float*)d_in[12];
    const float* qkv2_w = (const float*)d_in[13];
    const float* qkv2_b = (const float*)d_in[14];
    const float* out2_w = (const float*)d_in[15];
    const float* out2_b = (const float*)d_in[16];
    const float* mlp1_w1 = (const float*)d_in[17];
    const float* mlp1_b1 = (const float*)d_in[18];
    const float* mlp1_w2 = (const float*)d_in[19];
    const float* mlp1_b2 = (const float*)d_in[20];
    const float* mlp2_w1 = (const float*)d_in[21];
    const float* mlp2_b1 = (const float*)d_in[22];
    const float* mlp2_w2 = (const float*)d_in[23];
    const float* mlp2_b2 = (const float*)d_in[24];

    // bf16 weights in d_ws (786 KiB total)
    u16* wb = (u16*)d_ws;
    u16* qkv1bf = wb + 0;
    u16* out1bf = wb + 49152;
    u16* m1w1bf = wb + 65536;
    u16* m1w2bf = wb + 131072;
    u16* qkv2bf = wb + 196608;
    u16* out2bf = wb + 245760;
    u16* m2w1bf = wb + 262144;
    u16* m2w2bf = wb + 327680;

    float* out = (float*)d_out;

    cvt_weights<<<dim3(192), dim3(256), 0, stream>>>(
        qkv1_w, out1_w, mlp1_w1, mlp1_w2, qkv2_w, out2_w, mlp2_w1, mlp2_w2, wb);

    // K1: W-MSA + MLP1 -> out1 (writes every element of d_out; res1 never hits HBM)
    swin_fused<1><<<dim3(1024), dim3(512), 0, stream>>>(
        x, x, out,
        ln1_g, ln1_b, ln2_g, ln2_b,
        qkv1bf, qkv1_b, out1bf, out1_b,
        m1w1bf, mlp1_b1, m1w2bf, mlp1_b2);

    // K2: SW-MSA + MLP2 -> out2, in place on d_out (each block's gather set ==
    // its scatter set; blocks partition the row space -> no cross-block hazard)
    swin_fused<2><<<dim3(1024), dim3(512), 0, stream>>>(
        out, out, out,
        ln3_g, ln3_b, ln4_g, ln4_b,
        qkv2bf, qkv2_b, out2bf, out2_b,
        m2w1bf, mlp2_b1, m2w2bf, mlp2_b2);
}

// Round 7
// 278.062 us; speedup vs baseline: 1.7673x; 1.2631x over previous
//
#include <hip/hip_runtime.h>

// B=8, N=16384 (H=W=128), D=128, WS=4 -> nW=1024, P=16 tok/window, NH=2, dh=64.
// Two fused kernels (K1: LN1+W-MSA+res1+LN2+MLP1; K2: LN3+SW-MSA+res2+LN4+MLP2).
// Block = 64 tokens (4 windows), 512 threads (8 waves), LDS 72K -> 2 blocks/CU.

typedef unsigned short u16;
typedef unsigned int   u32;
typedef __attribute__((ext_vector_type(8))) short bf16x8;
typedef __attribute__((ext_vector_type(4))) float f32x4;

#define MFMA(a,b,c) __builtin_amdgcn_mfma_f32_16x16x32_bf16(a,b,c,0,0,0)

__device__ __forceinline__ u16 f2bf(float x) {           // RNE fp32->bf16
    u32 u = __float_as_uint(x);
    return (u16)((u + 0x7FFFu + ((u >> 16) & 1u)) >> 16);
}
__device__ __forceinline__ u32 pack2(float lo, float hi) {
    return (u32)f2bf(lo) | ((u32)f2bf(hi) << 16);
}
// tanh-form GELU via hw exp2 + rcp. |err| vs exact erf-GELU < ~1e-3.
__device__ __forceinline__ float gelu_fast(float x) {
    float t = x * fmaf(x * x, 0.044715f, 1.0f);
    float e = __builtin_amdgcn_exp2f(-2.3022078f * t);
    return x * __builtin_amdgcn_rcpf(1.0f + e);
}
__device__ __forceinline__ bf16x8 ldsfrag(const u16* base, int byte) {
    return *(const bf16x8*)((const char*)base + byte);
}
__device__ __forceinline__ bf16x8 ldg8(const u16* __restrict__ p) {
    return *(const bf16x8*)p;
}
// wg in [0,256): group of 4 windows; tok in [0,64).
// branch 1: image-order flat index; branch 2: roll(-2,-2)-mapped window-order index.
template <int BRANCH>
__device__ __forceinline__ int src_index(int wg, int tok) {
    int win = (wg << 2) + (tok >> 4), p = tok & 15;
    int r = ((win >> 5) << 2) | (p >> 2);
    int c = ((win & 31) << 2) | (p & 3);
    if (BRANCH == 1) return (r << 7) | c;
    int r2 = (r + 2) & 127, c2 = (c + 2) & 127;
    return ((((r2 >> 2) << 5) | (c2 >> 2)) << 4) | ((r2 & 3) << 2) | (c2 & 3);
}

// ---------------------------------------------------------------------------
// Weight fp32 -> bf16 prep.
// ---------------------------------------------------------------------------
__global__ __launch_bounds__(256)
void cvt_weights(const float* __restrict__ qkv1, const float* __restrict__ o1,
                 const float* __restrict__ w11,  const float* __restrict__ w12,
                 const float* __restrict__ qkv2, const float* __restrict__ o2,
                 const float* __restrict__ w21,  const float* __restrict__ w22,
                 u16* __restrict__ dst)
{
    int e = (blockIdx.x * 256 + threadIdx.x) * 8;
    const float* src; int off;
    if      (e < 49152)  { src = qkv1; off = 0; }
    else if (e < 65536)  { src = o1;   off = 49152; }
    else if (e < 131072) { src = w11;  off = 65536; }
    else if (e < 196608) { src = w12;  off = 131072; }
    else if (e < 245760) { src = qkv2; off = 196608; }
    else if (e < 262144) { src = o2;   off = 245760; }
    else if (e < 327680) { src = w21;  off = 262144; }
    else                 { src = w22;  off = 327680; }
    float4 a = *(const float4*)(src + (e - off));
    float4 b = *(const float4*)(src + (e - off) + 4);
    uint4 o;
    o.x = pack2(a.x, a.y); o.y = pack2(a.z, a.w);
    o.z = pack2(b.x, b.y); o.w = pack2(b.z, b.w);
    *(uint4*)(dst + e) = o;
}

// ---------------------------------------------------------------------------
// Fused half-block: LN_A + windowed MHSA + residual(LDS) + LN_B + MLP.
// LDS (73728 B): xs[64][256B]@0 | qls[64][256B]@16K | kls[64][256B]@32K |
//                vt[128][192B]@48K.  Overlays: resf fp32 [64][512B] = qls+kls;
//                P [64][128B] = qls; h1 [64][256B] = vt (first 16K).
// ---------------------------------------------------------------------------
template <int BRANCH>
__global__ __launch_bounds__(512, 4)
void swin_fused(const float* __restrict__ xin,   // LN_A source
                const float* __restrict__ resin, // residual source
                float* __restrict__ resout,      // output
                const float* __restrict__ lnA_g, const float* __restrict__ lnA_b,
                const float* __restrict__ lnB_g, const float* __restrict__ lnB_b,
                const u16* __restrict__ qkvw, const float* __restrict__ qkvb,
                const u16* __restrict__ ow,   const float* __restrict__ ob,
                const u16* __restrict__ w1,   const float* __restrict__ b1,
                const u16* __restrict__ w2,   const float* __restrict__ b2)
{
    __shared__ __align__(16) char smem[73728];
    u16*   xs   = (u16*)smem;
    u16*   qls  = (u16*)(smem + 16384);
    u16*   kls  = (u16*)(smem + 32768);
    u16*   vt   = (u16*)(smem + 49152);
    float* resf = (float*)(smem + 16384);
    u16*   h1   = (u16*)(smem + 49152);

    const int t  = threadIdx.x;
    const int wv = t >> 6, ln = t & 63, l15 = ln & 15, q4 = ln >> 4;
    const int bb = blockIdx.x >> 8, wg = blockIdx.x & 255;
    const int xa = (l15 & 7) << 4;
    const size_t gbase = (size_t)bb * 16384;

    // ---------- phase 0: gather + LN_A -> xs (bf16); zero vt pad ----------
    {
        int token = t >> 3, part = t & 7;               // 8 thr/token, 16 dims each
        int nsrc = src_index<BRANCH>(wg, token);
        const float* src = xin + (gbase + nsrc) * 128;
        float v[16];
#pragma unroll
        for (int j = 0; j < 4; ++j)
            *(float4*)&v[j * 4] = *(const float4*)(src + part * 4 + 32 * j);
        float s = 0.f, s2 = 0.f;
#pragma unroll
        for (int i = 0; i < 16; ++i) { s += v[i]; s2 += v[i] * v[i]; }
        s  += __shfl_xor(s, 1, 8);  s  += __shfl_xor(s, 2, 8);  s  += __shfl_xor(s, 4, 8);
        s2 += __shfl_xor(s2, 1, 8); s2 += __shfl_xor(s2, 2, 8); s2 += __shfl_xor(s2, 4, 8);
        float mu = s * (1.f / 128.f);
        float rstd = rsqrtf(s2 * (1.f / 128.f) - mu * mu + 1e-5f);
        int xk = (token & 7) << 4;
#pragma unroll
        for (int j = 0; j < 4; ++j) {
            int d0 = part * 4 + 32 * j;
            float a0 = (v[j * 4 + 0] - mu) * rstd * lnA_g[d0]     + lnA_b[d0];
            float a1 = (v[j * 4 + 1] - mu) * rstd * lnA_g[d0 + 1] + lnA_b[d0 + 1];
            float a2 = (v[j * 4 + 2] - mu) * rstd * lnA_g[d0 + 2] + lnA_b[d0 + 2];
            float a3 = (v[j * 4 + 3] - mu) * rstd * lnA_g[d0 + 3] + lnA_b[d0 + 3];
            int byte = token * 256 + ((part * 8 + j * 64) ^ xk);
            *(uint2*)((char*)xs + byte) = make_uint2(pack2(a0, a1), pack2(a2, a3));
        }
        // zero vt pad: rows [all dh], token bytes [128,192)
        int row = t >> 2, slot = t & 3;
        int byte = row * 192 + ((128 + slot * 16) ^ ((row & 7) << 4));
        uint4 z = {0, 0, 0, 0};
        *(uint4*)((char*)vt + byte) = z;
    }
    __syncthreads();

    // ---------- phase 1: QKV GEMM (M=64, N=384, K=128) ----------
#pragma unroll 1
    for (int i = 0; i < 3; ++i) {
        int n0 = (wv * 3 + i) * 16;
        int part = n0 >> 7, c0 = n0 & 127;
        float bias = qkvb[n0 + l15];
        f32x4 acc[4];
#pragma unroll
        for (int mf = 0; mf < 4; ++mf) acc[mf] = (f32x4){bias, bias, bias, bias};
#pragma unroll
        for (int kf = 0; kf < 4; ++kf) {
            bf16x8 bfr = ldg8(qkvw + (size_t)(n0 + l15) * 128 + kf * 32 + q4 * 8);
#pragma unroll
            for (int mf = 0; mf < 4; ++mf) {
                bf16x8 afr = ldsfrag(xs, (mf * 16 + l15) * 256 + ((kf * 64 + q4 * 16) ^ xa));
                acc[mf] = MFMA(afr, bfr, acc[mf]);
            }
        }
        if (part < 2) {                       // q (scaled) / k, token-major
            u16* dst = part ? kls : qls;
            float sc = part ? 1.f : 0.125f;
#pragma unroll
            for (int mf = 0; mf < 4; ++mf)
#pragma unroll
                for (int r = 0; r < 4; ++r) {
                    int tok = mf * 16 + q4 * 4 + r;
                    int byte = tok * 256 + ((2 * (c0 + l15)) ^ ((tok & 7) << 4));
                    dst[byte >> 1] = f2bf(acc[mf][r] * sc);
                }
        } else {                              // v -> vt[dh][tok], 192B stride
            int dh = c0 + l15, xr = (dh & 7) << 4;
#pragma unroll
            for (int mf = 0; mf < 4; ++mf) {
                int tok0 = mf * 16 + q4 * 4;
                u32 lo = pack2(acc[mf][0], acc[mf][1]);
                u32 hi = pack2(acc[mf][2], acc[mf][3]);
                int byte = dh * 192 + ((2 * tok0) ^ xr);
                *(uint2*)((char*)vt + byte) = make_uint2(lo, hi);
            }
        }
    }
    __syncthreads();

    // ---------- phase 2: scores. 1 (window,head) pair per wave ----------
    f32x4 S;
    {
        int win = wv >> 1, h = wv & 1;
        f32x4 z = {0.f, 0.f, 0.f, 0.f};
        int tok = win * 16 + l15, xk = (tok & 7) << 4;
#pragma unroll
        for (int kf = 0; kf < 2; ++kf) {
            int byte = tok * 256 + ((h * 128 + kf * 64 + q4 * 16) ^ xk);
            bf16x8 aq = ldsfrag(qls, byte);
            bf16x8 bk = ldsfrag(kls, byte);
            z = MFMA(aq, bk, z);
        }
        S = z;
    }
    __syncthreads();   // q reads done before P overlays qls

    // ---------- softmax in-register; P (bf16, K padded to 32) -> qls ----------
    {
        int win = wv >> 1, h = wv & 1;
#pragma unroll
        for (int r = 0; r < 4; ++r) {
            float v = S[r];
            float m = v;
            m = fmaxf(m, __shfl_xor(m, 1, 16)); m = fmaxf(m, __shfl_xor(m, 2, 16));
            m = fmaxf(m, __shfl_xor(m, 4, 16)); m = fmaxf(m, __shfl_xor(m, 8, 16));
            float e = __builtin_amdgcn_exp2f((v - m) * 1.44269504f);
            float sm = e;
            sm += __shfl_xor(sm, 1, 16); sm += __shfl_xor(sm, 2, 16);
            sm += __shfl_xor(sm, 4, 16); sm += __shfl_xor(sm, 8, 16);
            float p = e * __builtin_amdgcn_rcpf(sm);
            int tok = win * 16 + q4 * 4 + r, xk = (tok & 7) << 4;
            qls[(tok * 128 + ((h * 64 + l15 * 2)      ^ xk)) >> 1] = f2bf(p);
            qls[(tok * 128 + ((h * 64 + 32 + l15 * 2) ^ xk)) >> 1] = 0;
        }
    }
    __syncthreads();

    // ---------- phase 3: PV -> xs (attn-out bf16) ----------
    {
        int win = wv >> 1, h = wv & 1;
        int atok = win * 16 + l15;
        bf16x8 ap = ldsfrag(qls, atok * 128 + ((h * 64 + q4 * 16) ^ ((atok & 7) << 4)));
#pragma unroll
        for (int nf = 0; nf < 4; ++nf) {
            int dh = h * 64 + nf * 16 + l15;
            bf16x8 bv = ldsfrag(vt, dh * 192 + ((win * 32 + q4 * 16) ^ ((dh & 7) << 4)));
            f32x4 z = {0.f, 0.f, 0.f, 0.f};
            f32x4 o = MFMA(ap, bv, z);
#pragma unroll
            for (int r = 0; r < 4; ++r) {
                int tok = win * 16 + q4 * 4 + r;
                xs[(tok * 256 + ((2 * dh) ^ ((tok & 7) << 4))) >> 1] = f2bf(o[r]);
            }
        }
    }
    __syncthreads();

    // ---------- phase 4: output projection + residual -> resf (LDS fp32) ----------
    {
        int n0 = wv * 16;
        float bias = ob[n0 + l15];
        f32x4 acc[4];
#pragma unroll
        for (int mf = 0; mf < 4; ++mf) acc[mf] = (f32x4){bias, bias, bias, bias};
#pragma unroll
        for (int kf = 0; kf < 4; ++kf) {
            bf16x8 bfr = ldg8(ow + (size_t)(n0 + l15) * 128 + kf * 32 + q4 * 8);
#pragma unroll
            for (int mf = 0; mf < 4; ++mf) {
                bf16x8 afr = ldsfrag(xs, (mf * 16 + l15) * 256 + ((kf * 64 + q4 * 16) ^ xa));
                acc[mf] = MFMA(afr, bfr, acc[mf]);
            }
        }
#pragma unroll
        for (int mf = 0; mf < 4; ++mf)
#pragma unroll
            for (int r = 0; r < 4; ++r) {
                int tok = mf * 16 + q4 * 4 + r;
                int nd = (BRANCH == 1) ? (wg * 64 + tok) : src_index<2>(wg, tok);
                float rv = resin[(gbase + nd) * 128 + n0 + l15];
                if (BRANCH == 1) rv = truncf(rv);
                int byte = tok * 512 + ((4 * (n0 + l15)) ^ ((tok & 7) << 4));
                *(float*)((char*)resf + byte) = rv + acc[mf][r];
            }
    }
    __syncthreads();

    // ---------- phase 5: LN_B over resf -> xs (bf16) ----------
    {
        int token = t >> 3, part = t & 7;
        int xk = (token & 7) << 4;
        float v[16];
#pragma unroll
        for (int j = 0; j < 4; ++j)
            *(float4*)&v[j * 4] =
                *(const float4*)((char*)resf + token * 512 + ((part * 16 + j * 128) ^ xk));
        float s = 0.f, s2 = 0.f;
#pragma unroll
        for (int i = 0; i < 16; ++i) { s += v[i]; s2 += v[i] * v[i]; }
        s  += __shfl_xor(s, 1, 8);  s  += __shfl_xor(s, 2, 8);  s  += __shfl_xor(s, 4, 8);
        s2 += __shfl_xor(s2, 1, 8); s2 += __shfl_xor(s2, 2, 8); s2 += __shfl_xor(s2, 4, 8);
        float mu = s * (1.f / 128.f);
        float rstd = rsqrtf(s2 * (1.f / 128.f) - mu * mu + 1e-5f);
#pragma unroll
        for (int j = 0; j < 4; ++j) {
            int d0 = part * 4 + 32 * j;
            float a0 = (v[j * 4 + 0] - mu) * rstd * lnB_g[d0]     + lnB_b[d0];
            float a1 = (v[j * 4 + 1] - mu) * rstd * lnB_g[d0 + 1] + lnB_b[d0 + 1];
            float a2 = (v[j * 4 + 2] - mu) * rstd * lnB_g[d0 + 2] + lnB_b[d0 + 2];
            float a3 = (v[j * 4 + 3] - mu) * rstd * lnB_g[d0 + 3] + lnB_b[d0 + 3];
            int byte = token * 256 + ((part * 8 + j * 64) ^ xk);
            *(uint2*)((char*)xs + byte) = make_uint2(pack2(a0, a1), pack2(a2, a3));
        }
    }
    __syncthreads();

    // ---------- phase 6: MLP, 4 chunks x 128 h1-cols; wave owns 16 cols ----------
    const int nm = wv * 16;
    f32x4 acc2[4];
    {
        float bias = b2[nm + l15];
#pragma unroll
        for (int mf = 0; mf < 4; ++mf) acc2[mf] = (f32x4){bias, bias, bias, bias};
    }
#pragma unroll 1
    for (int c = 0; c < 4; ++c) {
        f32x4 acc1[4];
        {
            float bias = b1[c * 128 + nm + l15];
#pragma unroll
            for (int mf = 0; mf < 4; ++mf) acc1[mf] = (f32x4){bias, bias, bias, bias};
        }
#pragma unroll
        for (int kf = 0; kf < 4; ++kf) {
            bf16x8 bfr = ldg8(w1 + (size_t)(c * 128 + nm + l15) * 128 + kf * 32 + q4 * 8);
#pragma unroll
            for (int mf = 0; mf < 4; ++mf) {
                bf16x8 afr = ldsfrag(xs, (mf * 16 + l15) * 256 + ((kf * 64 + q4 * 16) ^ xa));
                acc1[mf] = MFMA(afr, bfr, acc1[mf]);
            }
        }
        __syncthreads();   // prior GEMM2 reads of h1 complete
#pragma unroll
        for (int mf = 0; mf < 4; ++mf)
#pragma unroll
            for (int r = 0; r < 4; ++r) {
                int tok = mf * 16 + q4 * 4 + r;
                h1[(tok * 256 + ((2 * (nm + l15)) ^ ((tok & 7) << 4))) >> 1] =
                    f2bf(gelu_fast(acc1[mf][r]));
            }
        __syncthreads();   // h1 chunk ready
#pragma unroll
        for (int kf = 0; kf < 4; ++kf) {
            bf16x8 bfr = ldg8(w2 + (size_t)(nm + l15) * 512 + c * 128 + kf * 32 + q4 * 8);
#pragma unroll
            for (int mf = 0; mf < 4; ++mf) {
                bf16x8 afr = ldsfrag(h1, (mf * 16 + l15) * 256 + ((kf * 64 + q4 * 16) ^ xa));
                acc2[mf] = MFMA(afr, bfr, acc2[mf]);
            }
        }
    }

    // ---------- phase 7: out = gelu(acc2) + resf -> global ----------
#pragma unroll
    for (int mf = 0; mf < 4; ++mf)
#pragma unroll
        for (int r = 0; r < 4; ++r) {
            int tok = mf * 16 + q4 * 4 + r;
            int nd = (BRANCH == 1) ? (wg * 64 + tok) : src_index<2>(wg, tok);
            float res = *(const float*)((char*)resf +
                            tok * 512 + ((4 * (nm + l15)) ^ ((tok & 7) << 4)));
            resout[(gbase + nd) * 128 + nm + l15] = gelu_fast(acc2[mf][r]) + res;
        }
}

extern "C" void kernel_launch(void* const* d_in, const int* in_sizes, int n_in,
                              void* d_out, int out_size, void* d_ws, size_t ws_size,
                              hipStream_t stream) {
    (void)in_sizes; (void)n_in; (void)out_size; (void)ws_size;
    const float* x      = (const float*)d_in[0];
    const float* ln1_g  = (const float*)d_in[1];
    const float* ln1_b  = (const float*)d_in[2];
    const float* ln2_g  = (const float*)d_in[3];
    const float* ln2_b  = (const float*)d_in[4];
    const float* ln3_g  = (const float*)d_in[5];
    const float* ln3_b  = (const float*)d_in[6];
    const float* ln4_g  = (const float*)d_in[7];
    const float* ln4_b  = (const float*)d_in[8];
    const float* qkv1_w = (const float*)d_in[9];
    const float* qkv1_b = (const float*)d_in[10];
    const float* out1_w = (const float*)d_in[11];
    const float* out1_b = (const float*)d_in[12];
    const float* qkv2_w = (const float*)d_in[13];
    const float* qkv2_b = (const float*)d_in[14];
    const float* out2_w = (const float*)d_in[15];
    const float* out2_b = (const float*)d_in[16];
    const float* mlp1_w1 = (const float*)d_in[17];
    const float* mlp1_b1 = (const float*)d_in[18];
    const float* mlp1_w2 = (const float*)d_in[19];
    const float* mlp1_b2 = (const float*)d_in[20];
    const float* mlp2_w1 = (const float*)d_in[21];
    const float* mlp2_b1 = (const float*)d_in[22];
    const float* mlp2_w2 = (const float*)d_in[23];
    const float* mlp2_b2 = (const float*)d_in[24];

    // bf16 weights in d_ws (786 KiB total)
    u16* wb = (u16*)d_ws;
    u16* qkv1bf = wb + 0;
    u16* out1bf = wb + 49152;
    u16* m1w1bf = wb + 65536;
    u16* m1w2bf = wb + 131072;
    u16* qkv2bf = wb + 196608;
    u16* out2bf = wb + 245760;
    u16* m2w1bf = wb + 262144;
    u16* m2w2bf = wb + 327680;

    float* out = (float*)d_out;

    cvt_weights<<<dim3(192), dim3(256), 0, stream>>>(
        qkv1_w, out1_w, mlp1_w1, mlp1_w2, qkv2_w, out2_w, mlp2_w1, mlp2_w2, wb);

    // K1: W-MSA + MLP1 -> out1 (writes every element of d_out)
    swin_fused<1><<<dim3(2048), dim3(512), 0, stream>>>(
        x, x, out,
        ln1_g, ln1_b, ln2_g, ln2_b,
        qkv1bf, qkv1_b, out1bf, out1_b,
        m1w1bf, mlp1_b1, m1w2bf, mlp1_b2);

    // K2: SW-MSA + MLP2 -> out2, in place (block gather set == scatter set)
    swin_fused<2><<<dim3(2048), dim3(512), 0, stream>>>(
        out, out, out,
        ln3_g, ln3_b, ln4_g, ln4_b,
        qkv2bf, qkv2_b, out2bf, out2_b,
        m2w1bf, mlp2_b1, m2w2bf, mlp2_b2);
}